// Round 1
// baseline (1034.474 us; speedup 1.0000x reference)
//
#include <hip/hip_runtime.h>

#define NW 30000
#define ND 8192
#define DIM 300
#define DIM2 150
#define NNZA 600000
#define NNZX 524288
#define BN_SCALE 0.99999500003749971f

static inline int cdiv(int a, int b){ return (a + b - 1) / b; }

// ---------------- CSR build ----------------
__global__ void k_hist(const int* __restrict__ rows, int n, int* __restrict__ cnt){
  int i = blockIdx.x * blockDim.x + threadIdx.x;
  if (i < n) atomicAdd(&cnt[rows[i]], 1);
}

__global__ void k_copy_int(const int* __restrict__ a, int* __restrict__ b, int n){
  int i = blockIdx.x * blockDim.x + threadIdx.x;
  if (i < n) b[i] = a[i];
}

__global__ __launch_bounds__(1024) void k_scan(const int* __restrict__ cnt, int n, int* __restrict__ rp){
  __shared__ int sd[1024];
  __shared__ int carry;
  const int t = threadIdx.x;
  if (t == 0) carry = 0;
  __syncthreads();
  int nch = (n + 1023) >> 10;
  for (int c = 0; c < nch; ++c){
    int i = (c << 10) + t;
    int v = (i < n) ? cnt[i] : 0;
    sd[t] = v;
    __syncthreads();
    for (int o = 1; o < 1024; o <<= 1){
      int x = (t >= o) ? sd[t - o] : 0;
      __syncthreads();
      sd[t] += x;
      __syncthreads();
    }
    if (i < n) rp[i] = carry + sd[t] - v;
    __syncthreads();
    if (t == 1023) carry += sd[1023];
    __syncthreads();
  }
  if (t == 0) rp[n] = carry;
}

__global__ void k_scatter(const int* __restrict__ rows, const int* __restrict__ cols,
                          const float* __restrict__ vals, int n, int* __restrict__ cursor,
                          int* __restrict__ cs, float* __restrict__ vs){
  int i = blockIdx.x * blockDim.x + threadIdx.x;
  if (i < n){
    int r = rows[i];
    int p = atomicAdd(&cursor[r], 1);
    cs[p] = cols[i];
    vs[p] = vals[i];
  }
}

// ---------------- SpMM: one wave per output row, register accumulate ----------------
__global__ __launch_bounds__(256) void k_spmm(const int* __restrict__ rp, const int* __restrict__ cs,
        const float* __restrict__ vs, const float* __restrict__ Hin, float* __restrict__ Hout, int nrows){
  int wid = (blockIdx.x * blockDim.x + threadIdx.x) >> 6;
  int lane = threadIdx.x & 63;
  if (wid >= nrows) return;
  int s = rp[wid], e = rp[wid + 1];
  float a0 = 0.f, a1 = 0.f, a2 = 0.f, a3 = 0.f, a4 = 0.f;
  int d4 = 256 + lane;
  for (int k = s; k < e; ++k){
    int c = cs[k];
    float v = vs[k];
    const float* h = Hin + (size_t)c * DIM;
    a0 = fmaf(v, h[lane      ], a0);
    a1 = fmaf(v, h[lane +  64], a1);
    a2 = fmaf(v, h[lane + 128], a2);
    a3 = fmaf(v, h[lane + 192], a3);
    if (d4 < DIM) a4 = fmaf(v, h[d4], a4);
  }
  float* o = Hout + (size_t)wid * DIM;
  o[lane] = a0; o[lane + 64] = a1; o[lane + 128] = a2; o[lane + 192] = a3;
  if (d4 < DIM) o[d4] = a4;
}

// ---------------- GEMM: C[M,N] = act(A[M,K] @ W[N,K]^T), optional bias + eval-BN + relu ----
// 64x64 tile / block of 256 threads, 4x4 per thread, K-tiles of 16 staged transposed in LDS.
__global__ __launch_bounds__(256) void k_gemm(const float* __restrict__ A, const float* __restrict__ W,
        const float* __restrict__ bias, const float* __restrict__ bng, const float* __restrict__ bnb,
        float* __restrict__ C, int M, int N, int K, int relu){
  __shared__ float As[16][68];
  __shared__ float Bs[16][68];
  const int t = threadIdx.x;
  const int tx4 = (t & 15) << 2;
  const int ty4 = (t >> 4) << 2;
  const int m0 = blockIdx.y << 6, n0 = blockIdx.x << 6;
  const int lr = t >> 2;          // 0..63
  const int lc = (t & 3) << 2;    // 0,4,8,12
  float acc[4][4] = {};
  for (int k0 = 0; k0 < K; k0 += 16){
    int gk = k0 + lc;
    int gm = m0 + lr, gn = n0 + lr;
    float4 av, bv;
    if (gm < M && gk + 3 < K){
      av = *(const float4*)(A + (size_t)gm * K + gk);
    } else {
      av.x = (gm < M && gk     < K) ? A[(size_t)gm * K + gk    ] : 0.f;
      av.y = (gm < M && gk + 1 < K) ? A[(size_t)gm * K + gk + 1] : 0.f;
      av.z = (gm < M && gk + 2 < K) ? A[(size_t)gm * K + gk + 2] : 0.f;
      av.w = (gm < M && gk + 3 < K) ? A[(size_t)gm * K + gk + 3] : 0.f;
    }
    if (gn < N && gk + 3 < K){
      bv = *(const float4*)(W + (size_t)gn * K + gk);
    } else {
      bv.x = (gn < N && gk     < K) ? W[(size_t)gn * K + gk    ] : 0.f;
      bv.y = (gn < N && gk + 1 < K) ? W[(size_t)gn * K + gk + 1] : 0.f;
      bv.z = (gn < N && gk + 2 < K) ? W[(size_t)gn * K + gk + 2] : 0.f;
      bv.w = (gn < N && gk + 3 < K) ? W[(size_t)gn * K + gk + 3] : 0.f;
    }
    As[lc + 0][lr] = av.x; As[lc + 1][lr] = av.y; As[lc + 2][lr] = av.z; As[lc + 3][lr] = av.w;
    Bs[lc + 0][lr] = bv.x; Bs[lc + 1][lr] = bv.y; Bs[lc + 2][lr] = bv.z; Bs[lc + 3][lr] = bv.w;
    __syncthreads();
    #pragma unroll
    for (int kk = 0; kk < 16; ++kk){
      float4 va = *(const float4*)(&As[kk][ty4]);
      float4 vb = *(const float4*)(&Bs[kk][tx4]);
      acc[0][0] = fmaf(va.x, vb.x, acc[0][0]);
      acc[0][1] = fmaf(va.x, vb.y, acc[0][1]);
      acc[0][2] = fmaf(va.x, vb.z, acc[0][2]);
      acc[0][3] = fmaf(va.x, vb.w, acc[0][3]);
      acc[1][0] = fmaf(va.y, vb.x, acc[1][0]);
      acc[1][1] = fmaf(va.y, vb.y, acc[1][1]);
      acc[1][2] = fmaf(va.y, vb.z, acc[1][2]);
      acc[1][3] = fmaf(va.y, vb.w, acc[1][3]);
      acc[2][0] = fmaf(va.z, vb.x, acc[2][0]);
      acc[2][1] = fmaf(va.z, vb.y, acc[2][1]);
      acc[2][2] = fmaf(va.z, vb.z, acc[2][2]);
      acc[2][3] = fmaf(va.z, vb.w, acc[2][3]);
      acc[3][0] = fmaf(va.w, vb.x, acc[3][0]);
      acc[3][1] = fmaf(va.w, vb.y, acc[3][1]);
      acc[3][2] = fmaf(va.w, vb.z, acc[3][2]);
      acc[3][3] = fmaf(va.w, vb.w, acc[3][3]);
    }
    __syncthreads();
  }
  #pragma unroll
  for (int i = 0; i < 4; ++i){
    int m = m0 + ty4 + i;
    if (m >= M) continue;
    #pragma unroll
    for (int j = 0; j < 4; ++j){
      int n = n0 + tx4 + j;
      if (n >= N) continue;
      float v = acc[i][j];
      if (bias) v += bias[n];
      if (bng)  v = v * (bng[n] * BN_SCALE) + bnb[n];
      if (relu) v = fmaxf(v, 0.f);
      C[(size_t)m * N + n] = v;
    }
  }
}

// ---------------- residual + LayerNorm, output S = LN(0.3*emb + 0.7*H) + emb ----------------
__global__ __launch_bounds__(64) void k_res_ln(const float* __restrict__ emb, const float* __restrict__ Hin,
        const float* __restrict__ g, const float* __restrict__ b, float* __restrict__ S){
  int row = blockIdx.x;
  int lane = threadIdx.x;
  const float* e = emb + (size_t)row * DIM;
  const float* h = Hin + (size_t)row * DIM;
  float x[5], ev[5];
  float sum = 0.f, sq = 0.f;
  #pragma unroll
  for (int j = 0; j < 5; ++j){
    int d = j * 64 + lane;
    float v = 0.f, ee = 0.f;
    if (d < DIM){ ee = e[d]; v = 0.3f * ee + 0.7f * h[d]; }
    ev[j] = ee; x[j] = v; sum += v; sq = fmaf(v, v, sq);
  }
  #pragma unroll
  for (int o = 32; o > 0; o >>= 1){ sum += __shfl_down(sum, o); sq += __shfl_down(sq, o); }
  sum = __shfl(sum, 0); sq = __shfl(sq, 0);
  const float inv = 1.f / (float)DIM;
  float mu = sum * inv;
  float var = sq * inv - mu * mu;
  float rs = rsqrtf(var + 1e-5f);
  float* o = S + (size_t)row * DIM;
  #pragma unroll
  for (int j = 0; j < 5; ++j){
    int d = j * 64 + lane;
    if (d < DIM) o[d] = (x[j] - mu) * rs * g[d] + b[d] + ev[j];
  }
}

// ---------------- tiny classifier: [ND,150] @ [2,150]^T + b ----------------
__global__ void k_clf(const float* __restrict__ h2, const float* __restrict__ w,
                      const float* __restrict__ bias, float* __restrict__ out){
  int m = blockIdx.x * blockDim.x + threadIdx.x;
  if (m >= ND) return;
  const float* hr = h2 + (size_t)m * DIM2;
  float s0 = bias[0], s1 = bias[1];
  for (int k = 0; k < DIM2; ++k){
    float hv = hr[k];
    s0 = fmaf(hv, w[k], s0);
    s1 = fmaf(hv, w[DIM2 + k], s1);
  }
  out[m * 2] = s0;
  out[m * 2 + 1] = s1;
}

extern "C" void kernel_launch(void* const* d_in, const int* in_sizes, int n_in,
                              void* d_out, int out_size, void* d_ws, size_t ws_size,
                              hipStream_t stream){
  const int*   a_rows = (const int*)  d_in[0];
  const int*   a_cols = (const int*)  d_in[1];
  const float* a_vals = (const float*)d_in[2];
  const int*   x_rows = (const int*)  d_in[3];
  const int*   x_cols = (const int*)  d_in[4];
  const float* x_vals = (const float*)d_in[5];
  const float* emb    = (const float*)d_in[6];
  const float* w1     = (const float*)d_in[7];
  const float* w2     = (const float*)d_in[8];
  const float* w3     = (const float*)d_in[9];
  const float* ln_g   = (const float*)d_in[10];
  const float* ln_b   = (const float*)d_in[11];
  const float* m_w1   = (const float*)d_in[12];
  const float* m_b1   = (const float*)d_in[13];
  const float* bn1_g  = (const float*)d_in[14];
  const float* bn1_b  = (const float*)d_in[15];
  const float* m_w2   = (const float*)d_in[16];
  const float* m_b2   = (const float*)d_in[17];
  const float* bn2_g  = (const float*)d_in[18];
  const float* bn2_b  = (const float*)d_in[19];
  const float* clf_w  = (const float*)d_in[20];
  const float* clf_b  = (const float*)d_in[21];
  float* out = (float*)d_out;

  char* ws = (char*)d_ws;
  size_t off = 0;
  auto take = [&](size_t nbytes)->void*{
    void* p = ws + off;
    off += (nbytes + 255) & ~(size_t)255;
    return p;
  };
  int*   a_rp   = (int*)  take((NW + 1) * sizeof(int));
  int*   a_cs   = (int*)  take((size_t)NNZA * 4);
  float* a_vs   = (float*)take((size_t)NNZA * 4);
  int*   x_rp   = (int*)  take((ND + 1) * sizeof(int));
  int*   x_cs   = (int*)  take((size_t)NNZX * 4);
  float* x_vs   = (float*)take((size_t)NNZX * 4);
  int*   cursor = (int*)  take((size_t)NW * 4);
  float* T      = (float*)take((size_t)NW * DIM * 4);
  float* H      = (float*)take((size_t)NW * DIM * 4);
  float* docH = H;                         // H3 is dead by the time these are written
  float* h1   = H + (size_t)ND * DIM;
  float* h2   = H + (size_t)2 * ND * DIM;

  // ---- build CSR for A ----
  hipMemsetAsync(cursor, 0, NW * 4, stream);
  k_hist<<<cdiv(NNZA, 256), 256, 0, stream>>>(a_rows, NNZA, cursor);
  k_scan<<<1, 1024, 0, stream>>>(cursor, NW, a_rp);
  k_copy_int<<<cdiv(NW, 256), 256, 0, stream>>>(a_rp, cursor, NW);
  k_scatter<<<cdiv(NNZA, 256), 256, 0, stream>>>(a_rows, a_cols, a_vals, NNZA, cursor, a_cs, a_vs);
  // ---- build CSR for X ----
  hipMemsetAsync(cursor, 0, ND * 4, stream);
  k_hist<<<cdiv(NNZX, 256), 256, 0, stream>>>(x_rows, NNZX, cursor);
  k_scan<<<1, 1024, 0, stream>>>(cursor, ND, x_rp);
  k_copy_int<<<cdiv(ND, 256), 256, 0, stream>>>(x_rp, cursor, ND);
  k_scatter<<<cdiv(NNZX, 256), 256, 0, stream>>>(x_rows, x_cols, x_vals, NNZX, cursor, x_cs, x_vs);

  dim3 gg(cdiv(DIM, 64), cdiv(NW, 64));
  // ---- word GCN ----
  k_spmm<<<cdiv(NW, 4), 256, 0, stream>>>(a_rp, a_cs, a_vs, emb, T, NW);
  k_gemm<<<gg, 256, 0, stream>>>(T, w1, nullptr, nullptr, nullptr, H, NW, DIM, DIM, 1);
  k_spmm<<<cdiv(NW, 4), 256, 0, stream>>>(a_rp, a_cs, a_vs, H, T, NW);
  k_gemm<<<gg, 256, 0, stream>>>(T, w2, nullptr, nullptr, nullptr, H, NW, DIM, DIM, 1);
  k_spmm<<<cdiv(NW, 4), 256, 0, stream>>>(a_rp, a_cs, a_vs, H, T, NW);
  k_gemm<<<gg, 256, 0, stream>>>(T, w3, nullptr, nullptr, nullptr, H, NW, DIM, DIM, 1);
  // ---- residual + LN; S = word_H + emb (fuses the two doc SpMMs into one) ----
  k_res_ln<<<NW, 64, 0, stream>>>(emb, H, ln_g, ln_b, T);
  // ---- doc aggregation ----
  k_spmm<<<cdiv(ND, 4), 256, 0, stream>>>(x_rp, x_cs, x_vs, T, docH, ND);
  // ---- MLP head ----
  dim3 g1(cdiv(DIM, 64), cdiv(ND, 64));
  k_gemm<<<g1, 256, 0, stream>>>(docH, m_w1, m_b1, bn1_g, bn1_b, h1, ND, DIM, DIM, 1);
  dim3 g2(cdiv(DIM2, 64), cdiv(ND, 64));
  k_gemm<<<g2, 256, 0, stream>>>(h1, m_w2, m_b2, bn2_g, bn2_b, h2, ND, DIM2, DIM, 1);
  k_clf<<<cdiv(ND, 256), 256, 0, stream>>>(h2, clf_w, clf_b, out);
}